// Round 6
// baseline (16.866 us; speedup 1.0000x reference)
//
#include <hip/hip_runtime.h>

// GraphSAGE encoder forward, v6: fused MFMA kernel + hoisted B-fragments.
//  v1 25.8us LDS-broadcast GEMM; v2 40.2; v3 33.1; v4 38.2 (see journal)
//  v5 16.4us: mfma_f32_16x16x32_bf16 GEMM, W loaded+converted AFTER gather sync
//     -> chip-wide phase serialization (HBM idle during GEMM phase).
//  v6: hoist W loads + f2bf conversion ABOVE the gather rows. W L2 traffic and
//     ~400 convert VALU ops hide under gather HBM latency; post-sync tail is
//     just 8 ds_read_b128 + 16 MFMA + epilogue.
//
// Inputs: emb f32[1M,128], neigh_w f32[8192,10], W f32[256,128], b f32[128],
//         nodes i32[8192], neigh_ids i32[8192,10]. Out f32[8192,128].

#define B_NODES 8192
#define K_NEIGH 10
#define FDIM 128
#define EDIM 128
#define NPB 16
#define THREADS 256

typedef __attribute__((ext_vector_type(8))) short short8v;  // 8 bf16 (4 VGPR)
typedef __attribute__((ext_vector_type(4))) float float4v;  // mfma acc

// XOR-swizzle byte addr (rows are 512B): breaks bank conflicts on A-frag reads.
// Same map on write and read sides.
__device__ __forceinline__ int swz(int byte) {
    return byte ^ (((byte >> 9) & 7) << 4);
}

// f32 -> bf16 bits, round-to-nearest-even
__device__ __forceinline__ short f2bf(float f) {
    unsigned u = __builtin_bit_cast(unsigned, f);
    u += 0x7FFFu + ((u >> 16) & 1u);
    return (short)(u >> 16);
}

__global__ __launch_bounds__(THREADS, 2) void sage_fused(
    const float* __restrict__ emb,
    const float* __restrict__ neigh_w,
    const float* __restrict__ Wm,
    const float* __restrict__ bias,
    const int*   __restrict__ nodes,
    const int*   __restrict__ neigh_ids,
    float* __restrict__ out)
{
    __shared__ __align__(16) short x_lds[NPB * 2 * FDIM];   // bf16 X tile, 8 KB
    char* xb = (char*)x_lds;

    const int tid = threadIdx.x;
    const int nb0 = blockIdx.x * NPB;

    // ---- GEMM lane mapping (used pre- and post-sync) -----------------------
    const int l    = tid & 63;
    const int wave = tid >> 6;
    const int lg   = l >> 4;             // k-group / row-group (0..3)
    const int li   = l & 15;
    const int e0   = wave * 32;          // this wave's 32 output cols

    // ================= B-fragments: load + convert W EARLY ==================
    // Independent of the gather; L2 loads + cvt VALU hide under gather latency.
    // B-frag: lane l -> W[k=(l>>4)*8+j][e0 + {li, 16+li}]
    short8v Bf0[8], Bf1[8];
#pragma unroll
    for (int kblk = 0; kblk < 8; ++kblk) {
        const int kb = kblk * 32 + lg * 8;
        short8v b0, b1;
#pragma unroll
        for (int j = 0; j < 8; ++j) {
            b0[j] = f2bf(Wm[(size_t)(kb + j) * EDIM + e0 + li]);
            b1[j] = f2bf(Wm[(size_t)(kb + j) * EDIM + e0 + 16 + li]);
        }
        Bf0[kblk] = b0;
        Bf1[kblk] = b1;
    }
    const float bv0 = bias[e0 + li];
    const float bv1 = bias[e0 + 16 + li];

    // ================= Phase 1: gather + aggregate -> bf16 X tile ===========
    // half-wave (32 lanes) per 2 nodes; lane covers float4 (4 dims).
    {
        const int hw  = tid >> 5;          // 0..7
        const int l32 = tid & 31;
        const int d0  = l32 * 4;

        const int nA = hw * 2, nB = nA + 1;
        const int gA = nb0 + nA, gB = nb0 + nB;

        const int sidA = nodes[gA];
        const int sidB = nodes[gB];
        int idsA[K_NEIGH], idsB[K_NEIGH];
        float wA[K_NEIGH], wB[K_NEIGH];
#pragma unroll
        for (int k = 0; k < K_NEIGH; ++k) idsA[k] = neigh_ids[gA * K_NEIGH + k];
#pragma unroll
        for (int k = 0; k < K_NEIGH; ++k) idsB[k] = neigh_ids[gB * K_NEIGH + k];
        float wsA = 0.f, wsB = 0.f;
#pragma unroll
        for (int k = 0; k < K_NEIGH; ++k) { wA[k] = neigh_w[gA * K_NEIGH + k]; wsA += wA[k]; }
#pragma unroll
        for (int k = 0; k < K_NEIGH; ++k) { wB[k] = neigh_w[gB * K_NEIGH + k]; wsB += wB[k]; }
        const float invA = 1.f / wsA, invB = 1.f / wsB;

        // ---- node A rows ----
        {
            const float4 sv = *reinterpret_cast<const float4*>(&emb[(size_t)sidA * FDIM + d0]);
            float4 a = make_float4(0.f, 0.f, 0.f, 0.f);
#pragma unroll
            for (int k = 0; k < K_NEIGH; ++k) {
                const float4 v = *reinterpret_cast<const float4*>(&emb[(size_t)idsA[k] * FDIM + d0]);
                a.x = fmaf(wA[k], v.x, a.x); a.y = fmaf(wA[k], v.y, a.y);
                a.z = fmaf(wA[k], v.z, a.z); a.w = fmaf(wA[k], v.w, a.w);
            }
            ushort4 s4, g4;
            s4.x = (unsigned short)f2bf(sv.x); s4.y = (unsigned short)f2bf(sv.y);
            s4.z = (unsigned short)f2bf(sv.z); s4.w = (unsigned short)f2bf(sv.w);
            g4.x = (unsigned short)f2bf(a.x * invA); g4.y = (unsigned short)f2bf(a.y * invA);
            g4.z = (unsigned short)f2bf(a.z * invA); g4.w = (unsigned short)f2bf(a.w * invA);
            *reinterpret_cast<ushort4*>(xb + swz(nA * 512 + l32 * 8))       = s4;
            *reinterpret_cast<ushort4*>(xb + swz(nA * 512 + 256 + l32 * 8)) = g4;
        }
        // ---- node B rows ----
        {
            const float4 sv = *reinterpret_cast<const float4*>(&emb[(size_t)sidB * FDIM + d0]);
            float4 a = make_float4(0.f, 0.f, 0.f, 0.f);
#pragma unroll
            for (int k = 0; k < K_NEIGH; ++k) {
                const float4 v = *reinterpret_cast<const float4*>(&emb[(size_t)idsB[k] * FDIM + d0]);
                a.x = fmaf(wB[k], v.x, a.x); a.y = fmaf(wB[k], v.y, a.y);
                a.z = fmaf(wB[k], v.z, a.z); a.w = fmaf(wB[k], v.w, a.w);
            }
            ushort4 s4, g4;
            s4.x = (unsigned short)f2bf(sv.x); s4.y = (unsigned short)f2bf(sv.y);
            s4.z = (unsigned short)f2bf(sv.z); s4.w = (unsigned short)f2bf(sv.w);
            g4.x = (unsigned short)f2bf(a.x * invB); g4.y = (unsigned short)f2bf(a.y * invB);
            g4.z = (unsigned short)f2bf(a.z * invB); g4.w = (unsigned short)f2bf(a.w * invB);
            *reinterpret_cast<ushort4*>(xb + swz(nB * 512 + l32 * 8))       = s4;
            *reinterpret_cast<ushort4*>(xb + swz(nB * 512 + 256 + l32 * 8)) = g4;
        }
    }
    __syncthreads();

    // ================= Phase 2: A-frags from LDS, 16 MFMA, epilogue =========
    // A-frag: lane l -> X[row=l&15][k=(l>>4)*8+j] (one swizzled b128 read)
    // D:      lane l reg r -> out[row=(l>>4)*4+r][e0 + {li, 16+li}]
    {
        float4v acc0 = {0.f, 0.f, 0.f, 0.f};
        float4v acc1 = {0.f, 0.f, 0.f, 0.f};

#pragma unroll
        for (int kblk = 0; kblk < 8; ++kblk) {
            const short8v a = *reinterpret_cast<const short8v*>(
                xb + swz(li * 512 + kblk * 64 + lg * 16));
            acc0 = __builtin_amdgcn_mfma_f32_16x16x32_bf16(a, Bf0[kblk], acc0, 0, 0, 0);
            acc1 = __builtin_amdgcn_mfma_f32_16x16x32_bf16(a, Bf1[kblk], acc1, 0, 0, 0);
        }

#pragma unroll
        for (int r = 0; r < 4; ++r) {
            const int row = nb0 + lg * 4 + r;
            float v0 = acc0[r] + bv0;
            float v1 = acc1[r] + bv1;
            out[(size_t)row * EDIM + e0 + li]      = v0 / (1.f + __expf(-v0));
            out[(size_t)row * EDIM + e0 + 16 + li] = v1 / (1.f + __expf(-v1));
        }
    }
}

extern "C" void kernel_launch(void* const* d_in, const int* in_sizes, int n_in,
                              void* d_out, int out_size, void* d_ws, size_t ws_size,
                              hipStream_t stream) {
    const float* emb       = (const float*)d_in[0];
    const float* neigh_w   = (const float*)d_in[1];
    const float* Wm        = (const float*)d_in[2];
    const float* bias      = (const float*)d_in[3];
    const int*   nodes     = (const int*)d_in[4];
    const int*   neigh_ids = (const int*)d_in[5];
    float* out = (float*)d_out;

    sage_fused<<<dim3(B_NODES / NPB), dim3(THREADS), 0, stream>>>(
        emb, neigh_w, Wm, bias, nodes, neigh_ids, out);
}

// Round 7
// 16.257 us; speedup vs baseline: 1.0375x; 1.0375x over previous
//
#include <hip/hip_runtime.h>

// GraphSAGE encoder forward, v7: fused MFMA kernel, 8-wave blocks.
//  v1 25.8 (LDS-GEMM ~10us + gather ~15us); v2 40.2; v3 33.1; v4 38.2;
//  v5 16.4 (MFMA GEMM, 4-wave blocks, 8 waves/CU);
//  v6 16.9 (hoisted B-frags: neutral -> GEMM tail was not the gap).
//  Diagnosis: gather runs at ~3 TB/s (46MB/~15us). v7 doubles waves/CU
//  (16) with lean float2 gathers to test concurrency vs DRAM-pattern wall.
//
// Inputs: emb f32[1M,128], neigh_w f32[8192,10], W f32[256,128], b f32[128],
//         nodes i32[8192], neigh_ids i32[8192,10]. Out f32[8192,128].

#define B_NODES 8192
#define K_NEIGH 10
#define FDIM 128
#define EDIM 128
#define NPB 16
#define THREADS 512

typedef __attribute__((ext_vector_type(8))) short short8v;  // 8 bf16 (4 VGPR)
typedef __attribute__((ext_vector_type(4))) float float4v;  // mfma acc

// XOR-swizzle byte addr (rows are 512B): breaks the stride-512B bank conflict
// on A-frag ds_read_b128. Same map on write and read sides.
__device__ __forceinline__ int swz(int byte) {
    return byte ^ (((byte >> 9) & 7) << 4);
}

// f32 -> bf16 bits, round-to-nearest-even
__device__ __forceinline__ short f2bf(float f) {
    unsigned u = __builtin_bit_cast(unsigned, f);
    u += 0x7FFFu + ((u >> 16) & 1u);
    return (short)(u >> 16);
}

__global__ __launch_bounds__(THREADS, 4) void sage_fused(
    const float* __restrict__ emb,
    const float* __restrict__ neigh_w,
    const float* __restrict__ Wm,
    const float* __restrict__ bias,
    const int*   __restrict__ nodes,
    const int*   __restrict__ neigh_ids,
    float* __restrict__ out)
{
    __shared__ __align__(16) short x_lds[NPB * 2 * FDIM];   // bf16 X tile, 8 KB
    char* xb = (char*)x_lds;

    const int tid  = threadIdx.x;
    const int nb0  = blockIdx.x * NPB;
    const int wv   = tid >> 6;          // wave 0..7
    const int l    = tid & 63;

    // ================= Phase 1: gather + aggregate -> bf16 X tile ===========
    // wave wv handles nodes 2wv, 2wv+1; lane covers 2 dims (float2, 512B/row).
    {
        const int d0 = l * 2;
#pragma unroll
        for (int nn = 0; nn < 2; ++nn) {
            const int nl = wv * 2 + nn;
            const int g  = nb0 + nl;

            // metadata: vectorized uniform loads (40B each, 8B-aligned)
            const int2*   ip = reinterpret_cast<const int2*>(neigh_ids + (size_t)g * K_NEIGH);
            const float2* wp = reinterpret_cast<const float2*>(neigh_w  + (size_t)g * K_NEIGH);
            int2   id2[5];
            float2 w2[5];
#pragma unroll
            for (int k = 0; k < 5; ++k) id2[k] = ip[k];
#pragma unroll
            for (int k = 0; k < 5; ++k) w2[k]  = wp[k];
            const int sid = nodes[g];

            float wsum = 0.f;
#pragma unroll
            for (int k = 0; k < 5; ++k) wsum += w2[k].x + w2[k].y;
            const float inv = 1.f / wsum;

            const float2 sv = *reinterpret_cast<const float2*>(&emb[(size_t)sid * FDIM + d0]);

            float ax = 0.f, ay = 0.f;
#pragma unroll
            for (int k = 0; k < 5; ++k) {
                const float2 vx = *reinterpret_cast<const float2*>(&emb[(size_t)id2[k].x * FDIM + d0]);
                const float2 vy = *reinterpret_cast<const float2*>(&emb[(size_t)id2[k].y * FDIM + d0]);
                ax = fmaf(w2[k].x, vx.x, ax); ay = fmaf(w2[k].x, vx.y, ay);
                ax = fmaf(w2[k].y, vy.x, ax); ay = fmaf(w2[k].y, vy.y, ay);
            }

            ushort2 s2, g2;
            s2.x = (unsigned short)f2bf(sv.x);      s2.y = (unsigned short)f2bf(sv.y);
            g2.x = (unsigned short)f2bf(ax * inv);  g2.y = (unsigned short)f2bf(ay * inv);
            *reinterpret_cast<ushort2*>(xb + swz(nl * 512 + l * 4))       = s2;
            *reinterpret_cast<ushort2*>(xb + swz(nl * 512 + 256 + l * 4)) = g2;
        }
    }
    __syncthreads();

    // ================= Phase 2: X[16,256] @ W[256,128] via MFMA =============
    // wave wv owns output cols [wv*16, wv*16+16): ONE 16x16 N-tile, 8 MFMAs.
    // A-frag: lane l -> X[row=l&15][k=(l>>4)*8+j] (one swizzled b128 read)
    // B-frag: lane l -> W[k=(l>>4)*8+j][wv*16 + (l&15)] (8 coalesced f32 loads)
    // D:      lane l reg r -> out[row=(l>>4)*4+r][wv*16 + (l&15)]
    {
        const int lg = l >> 4;           // k-group / row-group (0..3)
        const int li = l & 15;
        const int ec = wv * 16 + li;     // output column

        float4v acc = {0.f, 0.f, 0.f, 0.f};
#pragma unroll
        for (int kblk = 0; kblk < 8; ++kblk) {
            const short8v a = *reinterpret_cast<const short8v*>(
                xb + swz(li * 512 + kblk * 64 + lg * 16));

            const int kb = kblk * 32 + lg * 8;
            short8v b;
#pragma unroll
            for (int j = 0; j < 8; ++j)
                b[j] = f2bf(Wm[(size_t)(kb + j) * EDIM + ec]);

            acc = __builtin_amdgcn_mfma_f32_16x16x32_bf16(a, b, acc, 0, 0, 0);
        }

        const float bv = bias[ec];
#pragma unroll
        for (int r = 0; r < 4; ++r) {
            const int row = nb0 + lg * 4 + r;
            const float v = acc[r] + bv;
            out[(size_t)row * EDIM + ec] = v / (1.f + __expf(-v));
        }
    }
}

extern "C" void kernel_launch(void* const* d_in, const int* in_sizes, int n_in,
                              void* d_out, int out_size, void* d_ws, size_t ws_size,
                              hipStream_t stream) {
    const float* emb       = (const float*)d_in[0];
    const float* neigh_w   = (const float*)d_in[1];
    const float* Wm        = (const float*)d_in[2];
    const float* bias      = (const float*)d_in[3];
    const int*   nodes     = (const int*)d_in[4];
    const int*   neigh_ids = (const int*)d_in[5];
    float* out = (float*)d_out;

    sage_fused<<<dim3(B_NODES / NPB), dim3(THREADS), 0, stream>>>(
        emb, neigh_w, Wm, bias, nodes, neigh_ids, out);
}